// Round 10
// baseline (113.737 us; speedup 1.0000x reference)
//
#include <hip/hip_runtime.h>
#include <hip/hip_bf16.h>
#include <stdint.h>

typedef int i32x4 __attribute__((ext_vector_type(4)));

constexpr int IN_F = 1024;
constexpr int OUT_F = 1024;
constexpr int M_TOT = 8 * 4096;   // 32768 tokens
constexpr int K_TOT = IN_F;
constexpr int N_TOT = OUT_F;

// ---------------- kernel 1: per-token int8 fake-quant -> int8 q ----------------
__global__ __launch_bounds__(256) void quant_kernel(
    const float* __restrict__ x,
    const float* __restrict__ wscale,
    int8_t* __restrict__ q,            // [M_TOT][K_TOT] int8
    float* __restrict__ inv_row)       // [M_TOT]  (= a/127 * weight_scale)
{
    const int row = blockIdx.x;
    const int t = threadIdx.x;
    const float4 v = reinterpret_cast<const float4*>(x + (size_t)row * IN_F)[t];
    float m = fmaxf(fmaxf(fabsf(v.x), fabsf(v.y)), fmaxf(fabsf(v.z), fabsf(v.w)));
    #pragma unroll
    for (int off = 32; off > 0; off >>= 1)
        m = fmaxf(m, __shfl_xor(m, off));
    __shared__ float smax[4];
    if ((t & 63) == 0) smax[t >> 6] = m;
    __syncthreads();
    m = fmaxf(fmaxf(smax[0], smax[1]), fmaxf(smax[2], smax[3]));
    const float a = fmaxf(m, 1e-5f);
    const float as = 127.0f / a;

    char4 o;
    o.x = (char)(int)fminf(fmaxf(rintf(v.x * as), -128.0f), 127.0f);
    o.y = (char)(int)fminf(fmaxf(rintf(v.y * as), -128.0f), 127.0f);
    o.z = (char)(int)fminf(fmaxf(rintf(v.z * as), -128.0f), 127.0f);
    o.w = (char)(int)fminf(fmaxf(rintf(v.w * as), -128.0f), 127.0f);
    reinterpret_cast<char4*>(q + (size_t)row * IN_F)[t] = o;
    if (t == 0) inv_row[row] = (a / 127.0f) * wscale[0];
}

// ---------------- kernel 2: unpack ternary weights (bit-plane permuted) -> int8 ----------------
__global__ __launch_bounds__(256) void unpack_kernel(
    const int* __restrict__ packed,
    int8_t* __restrict__ wt)           // [OUT_F][IN_F] int8 in {-1,0,1} (B^T layout)
{
    const int o = blockIdx.x;
    const int k0 = threadIdx.x * 4;
    const int sh = (o >> 8) * 2;
    const int pbase = ((o & 255) << 10) + k0;
    const int4 pw = *reinterpret_cast<const int4*>(packed + pbase);
    char4 r;
    r.x = (char)(((pw.x >> sh) & 3) - 1);
    r.y = (char)(((pw.y >> sh) & 3) - 1);
    r.z = (char)(((pw.z >> sh) & 3) - 1);
    r.w = (char)(((pw.w >> sh) & 3) - 1);
    *reinterpret_cast<char4*>(wt + (size_t)o * IN_F + k0) = r;
}

// ---------------- kernel 3: DIAGNOSTIC build of the round-5 winner ----------------
// Identical structure to r5 (best: 86.8us total): 256x256, BK=128, i8 MFMA, 2 phases,
// 32-MFMA bursts, dbuf, involution swizzle. The K-pipeline runs TWICE accumulating:
// acc = 2x the true integer sum (exact; halved in the epilogue, even so exact).
// Both passes feed the output -> no DCE. Purpose: push this dispatch past the
// harness's ~75us fillBuffer poisons so rocprof top-5 shows its counters again.
constexpr int BM = 256, BN = 256, BK = 128;
constexpr int NT = K_TOT / BK;   // 8

__global__ __launch_bounds__(512, 2) void gemm_kernel(
    const int8_t* __restrict__ qa,     // [M_TOT][K_TOT] int8
    const int8_t* __restrict__ wb,     // [N_TOT][K_TOT] int8
    const float* __restrict__ inv_row,
    const float* __restrict__ bias,
    float* __restrict__ out)
{
    // XCD-aware swizzle: nwg = 512, divisible by 8 -> bijective simple remap
    int bid = blockIdx.x;
    bid = (bid & 7) * ((int)gridDim.x >> 3) + (bid >> 3);
    const int tm = bid >> 2;            // 0..127
    const int tn = bid & 3;             // 0..3

    const int tid = threadIdx.x;
    const int lane = tid & 63;
    const int wid = tid >> 6;           // 0..7
    const int wr = wid >> 2;            // 0..1 (M half: rows wr*128..)
    const int wc = wid & 3;             // 0..3 (N quarter: cols wc*64..)

    __shared__ int8_t lds[2][2][2][128 * 128];  // [buf][ab][region] 16 KiB each = 128 KiB

    const int rowA0 = tm * BM;
    const int rowB0 = tn * BN;
    const int frow = lane & 15;
    const int fq = lane >> 4;           // 0..3

    i32x4 acc[8][4] = {};

    // stage one 16 KiB region (128 local rows x 128 k): 2 global_load_lds per thread
    auto stage = [&](int buf, int ab, int region, int kt) {
        const int8_t* base = ab ? wb : qa;
        #pragma unroll
        for (int j = 0; j < 2; ++j) {
            const int c = j * 512 + tid;          // chunk 0..1023 (16B each)
            const int rl = c >> 3, cc = c & 7;
            const int grow = ab ? (rowB0 + region * 128 + rl)
                                : (rowA0 + (rl & 64) * 2 + region * 64 + (rl & 63));
            const int scc = cc ^ (rl & 7);        // inverse swizzle on global src
            const int8_t* src = base + (size_t)grow * K_TOT + kt * BK + scc * 16;
            __builtin_amdgcn_global_load_lds(
                (const __attribute__((address_space(1))) void*)src,
                (__attribute__((address_space(3))) void*)&lds[buf][ab][region][c * 16],
                16, 0, 0);
        }
    };

    auto ldA = [&](int buf, int region, int mf, int ks) -> i32x4 {
        const int local = wr * 64 + (mf & 3) * 16 + frow;
        const int ch = (ks * 4 + fq) ^ (local & 7);
        return *reinterpret_cast<const i32x4*>(&lds[buf][0][region][local * 128 + ch * 16]);
    };
    auto ldB = [&](int buf, int nf, int ks) -> i32x4 {
        const int region = wc >> 1;
        const int local = (wc & 1) * 64 + nf * 16 + frow;
        const int ch = (ks * 4 + fq) ^ (local & 7);
        return *reinterpret_cast<const i32x4*>(&lds[buf][1][region][local * 128 + ch * 16]);
    };

    #pragma unroll 1
    for (int rep = 0; rep < 2; ++rep) {
        // prologue: stage tile 0 fully (8 loads), drain, barrier
        stage(0, 1, 0, 0); stage(0, 1, 1, 0); stage(0, 0, 0, 0); stage(0, 0, 1, 0);
        asm volatile("s_waitcnt vmcnt(0)" ::: "memory");
        __builtin_amdgcn_s_barrier();

        #pragma unroll 1
        for (int T = 0; T < NT; ++T) {
            const int cur = T & 1, nxt = cur ^ 1;
            const bool st = (T + 1 < NT);
            i32x4 aF[4][2], bF[4][2];

            // ---- Ph0: read A-R0 (8) + B-all (8); stage nxt B; MFMA rows-lo (32)
            #pragma unroll
            for (int mf = 0; mf < 4; ++mf)
                #pragma unroll
                for (int ks = 0; ks < 2; ++ks)
                    aF[mf][ks] = ldA(cur, 0, mf, ks);
            #pragma unroll
            for (int nf = 0; nf < 4; ++nf)
                #pragma unroll
                for (int ks = 0; ks < 2; ++ks)
                    bF[nf][ks] = ldB(cur, nf, ks);
            if (st) { stage(nxt, 1, 0, T + 1); stage(nxt, 1, 1, T + 1); }
            __builtin_amdgcn_s_barrier();
            asm volatile("s_waitcnt lgkmcnt(0)" ::: "memory");
            __builtin_amdgcn_sched_barrier(0);
            __builtin_amdgcn_s_setprio(1);
            #pragma unroll
            for (int mf = 0; mf < 4; ++mf)
                #pragma unroll
                for (int nf = 0; nf < 4; ++nf)
                    #pragma unroll
                    for (int ks = 0; ks < 2; ++ks)
                        acc[mf][nf] = __builtin_amdgcn_mfma_i32_16x16x64_i8(
                            aF[mf][ks], bF[nf][ks], acc[mf][nf], 0, 0, 0);
            __builtin_amdgcn_s_setprio(0);
            if (st) asm volatile("s_waitcnt vmcnt(4)" ::: "memory");  // A-R1(T) certified
            else    asm volatile("s_waitcnt vmcnt(0)" ::: "memory");
            __builtin_amdgcn_s_barrier();

            // ---- Ph1: read A-R1 (8); stage nxt A; MFMA rows-hi (32)
            #pragma unroll
            for (int mf = 0; mf < 4; ++mf)
                #pragma unroll
                for (int ks = 0; ks < 2; ++ks)
                    aF[mf][ks] = ldA(cur, 1, mf, ks);
            if (st) { stage(nxt, 0, 0, T + 1); stage(nxt, 0, 1, T + 1); }
            __builtin_amdgcn_s_barrier();
            asm volatile("s_waitcnt lgkmcnt(0)" ::: "memory");
            __builtin_amdgcn_sched_barrier(0);
            __builtin_amdgcn_s_setprio(1);
            #pragma unroll
            for (int mf = 0; mf < 4; ++mf)
                #pragma unroll
                for (int nf = 0; nf < 4; ++nf)
                    #pragma unroll
                    for (int ks = 0; ks < 2; ++ks)
                        acc[4 + mf][nf] = __builtin_amdgcn_mfma_i32_16x16x64_i8(
                            aF[mf][ks], bF[nf][ks], acc[4 + mf][nf], 0, 0, 0);
            __builtin_amdgcn_s_setprio(0);
            asm volatile("s_waitcnt vmcnt(2)" ::: "memory");  // B(T+1)+A-R0(T+1) certified
            __builtin_amdgcn_s_barrier();
        }
        // rep boundary: all staging drained by last tile's vmcnt(0); extra barrier safe
        asm volatile("s_waitcnt vmcnt(0)" ::: "memory");
        __builtin_amdgcn_s_barrier();
    }

    // epilogue: C/D 16x16 layout: col = lane&15, row = fq*4 + reg.
    // acc = 2x true sum (exact, even) -> /2 restores exact integer result.
    #pragma unroll
    for (int mi = 0; mi < 8; ++mi) {
        #pragma unroll
        for (int j = 0; j < 4; ++j) {
            const int gm = rowA0 + wr * 128 + mi * 16 + fq * 4 + j;
            const float sc = inv_row[gm];
            #pragma unroll
            for (int nf = 0; nf < 4; ++nf) {
                const int gn = rowB0 + wc * 64 + nf * 16 + frow;
                out[(size_t)gm * N_TOT + gn] = (float)(acc[mi][nf][j] / 2) * sc + bias[gn];
            }
        }
    }
}

extern "C" void kernel_launch(void* const* d_in, const int* in_sizes, int n_in,
                              void* d_out, int out_size, void* d_ws, size_t ws_size,
                              hipStream_t stream) {
    const float* x = (const float*)d_in[0];
    const int* packed = (const int*)d_in[1];
    const float* wscale = (const float*)d_in[2];
    const float* bias = (const float*)d_in[3];
    float* out = (float*)d_out;

    int8_t* q = (int8_t*)d_ws;                                          // 32 MiB
    int8_t* wt = (int8_t*)((char*)d_ws + (size_t)M_TOT * K_TOT);        // 1 MiB
    float* inv_row = (float*)((char*)d_ws + (size_t)M_TOT * K_TOT + (size_t)N_TOT * K_TOT);

    quant_kernel<<<M_TOT, 256, 0, stream>>>(x, wscale, q, inv_row);
    unpack_kernel<<<OUT_F, 256, 0, stream>>>(packed, wt);
    gemm_kernel<<<(M_TOT / BM) * (N_TOT / BN), 512, 0, stream>>>(q, wt, inv_row, bias, out);
}

// Round 11
// 94.148 us; speedup vs baseline: 1.2081x; 1.2081x over previous
//
#include <hip/hip_runtime.h>
#include <hip/hip_bf16.h>
#include <stdint.h>

typedef int i32x4 __attribute__((ext_vector_type(4)));

constexpr int IN_F = 1024;
constexpr int OUT_F = 1024;
constexpr int M_TOT = 8 * 4096;   // 32768 tokens
constexpr int K_TOT = IN_F;
constexpr int N_TOT = OUT_F;

// ---------------- kernel 1: per-token int8 fake-quant -> int8 q ----------------
__global__ __launch_bounds__(256) void quant_kernel(
    const float* __restrict__ x,
    const float* __restrict__ wscale,
    int8_t* __restrict__ q,            // [M_TOT][K_TOT] int8
    float* __restrict__ inv_row)       // [M_TOT]  (= a/127 * weight_scale)
{
    const int row = blockIdx.x;
    const int t = threadIdx.x;
    const float4 v = reinterpret_cast<const float4*>(x + (size_t)row * IN_F)[t];
    float m = fmaxf(fmaxf(fabsf(v.x), fabsf(v.y)), fmaxf(fabsf(v.z), fabsf(v.w)));
    #pragma unroll
    for (int off = 32; off > 0; off >>= 1)
        m = fmaxf(m, __shfl_xor(m, off));
    __shared__ float smax[4];
    if ((t & 63) == 0) smax[t >> 6] = m;
    __syncthreads();
    m = fmaxf(fmaxf(smax[0], smax[1]), fmaxf(smax[2], smax[3]));
    const float a = fmaxf(m, 1e-5f);
    const float as = 127.0f / a;

    char4 o;
    o.x = (char)(int)fminf(fmaxf(rintf(v.x * as), -128.0f), 127.0f);
    o.y = (char)(int)fminf(fmaxf(rintf(v.y * as), -128.0f), 127.0f);
    o.z = (char)(int)fminf(fmaxf(rintf(v.z * as), -128.0f), 127.0f);
    o.w = (char)(int)fminf(fmaxf(rintf(v.w * as), -128.0f), 127.0f);
    reinterpret_cast<char4*>(q + (size_t)row * IN_F)[t] = o;
    if (t == 0) inv_row[row] = (a / 127.0f) * wscale[0];
}

// ---------------- kernel 2: unpack ternary -> B in MFMA-fragment order ----------------
// wt2 layout: [kt64(16)][col(1024)][kq(4)][kb(16)] so a wave's B-frag (col = base+(l&15),
// k = kt64*64 + (l>>4)*16 ..+15) is one per-lane 16B contiguous load; a wave reads 1KB
// contiguous. value = ((packed[(o&255)*1024 + k] >> (2*(o>>8))) & 3) - 1.  (r9-verified)
__global__ __launch_bounds__(256) void unpack_kernel(
    const int* __restrict__ packed,
    int8_t* __restrict__ wt2)          // 1 MiB
{
    const int o = blockIdx.x;
    const int t = threadIdx.x;
    const int k0 = t * 4;
    const int sh = (o >> 8) * 2;
    const int pbase = ((o & 255) << 10) + k0;
    const int4 pw = *reinterpret_cast<const int4*>(packed + pbase);
    char4 r;
    r.x = (char)(((pw.x >> sh) & 3) - 1);
    r.y = (char)(((pw.y >> sh) & 3) - 1);
    r.z = (char)(((pw.z >> sh) & 3) - 1);
    r.w = (char)(((pw.w >> sh) & 3) - 1);
    const int addr = (k0 >> 6) * 65536 + o * 64 + ((k0 >> 4) & 3) * 16 + (k0 & 15);
    *reinterpret_cast<char4*>(wt2 + addr) = r;
}

// ---------------- kernel 3: int8 MFMA GEMM, BM=128 x BN=256, BK=128 ----------------
// mfma_i32_16x16x64_i8. 8 waves (2M x 4N), 64x64/wave. B from fragment-ordered wt2
// straight to VGPR (L2-resident; zero B LDS traffic). LDS = A only, 3 slots x 16 KiB
// = 48 KiB -> 3 blocks/CU co-resident (24 waves/CU): C-writes overlap other blocks'
// K-loops; LDS demand 80 KiB / 1242 MFMA-cyc = 66 B/cyc << ds_read_b128 ceiling.
// Pipeline: A staged 2 K-tiles ahead (slot T%3), B loaded 1 tile ahead to regs.
// One barrier + one vmcnt(10) per K-tile. Audit: outstanding at top of T =
// {A(T):2, A(T+1):2, B(T):8} (issue order A older) -> vmcnt(10) retires A(T);
// B(T) certified by compiler auto-wait before first MFMA use; slot T+3 overwrite
// (iter T+1) ordered after all T-reads by the top-of-(T+1) barrier + per-wave lgkm(0).
// A swizzle: ch ^= (local&7) involution (r5-proven 0-conflict), linear LDS dest,
// inverse-swizzled global src (j-invariant: j*512 chunks -> rl += 64, (rl&7) const).
constexpr int BM = 128, BN = 256, BK = 128;
constexpr int NT = K_TOT / BK;   // 8

__global__ __launch_bounds__(512, 4) void gemm_kernel(
    const int8_t* __restrict__ qa,     // [M_TOT][K_TOT] int8
    const int8_t* __restrict__ wb2,    // fragment-ordered ternary weights (1 MiB)
    const float* __restrict__ inv_row,
    const float* __restrict__ bias,
    float* __restrict__ out)
{
    // XCD-aware swizzle: nwg = 1024, divisible by 8 -> bijective simple remap.
    // Consecutive remapped bids share tm -> same-XCD L2 reuse of A rows (4x).
    int bid = blockIdx.x;
    bid = (bid & 7) * ((int)gridDim.x >> 3) + (bid >> 3);
    const int tm = bid >> 2;            // 0..255
    const int tn = bid & 3;             // 0..3

    const int tid = threadIdx.x;
    const int lane = tid & 63;
    const int wid = tid >> 6;           // 0..7
    const int wr = wid >> 2;            // 0..1 (M half: rows wr*64..)
    const int wc = wid & 3;             // 0..3 (N quarter: cols wc*64..)

    __shared__ int8_t ldsA[3][128 * 128];   // 48 KiB

    const int rowA0 = tm * BM;
    const int rowB0 = tn * BN;
    const int frow = lane & 15;
    const int fq = lane >> 4;           // 0..3

    i32x4 acc[4][4] = {};

    // A staging: chunk c = j*512 + tid (16B); rl = c>>3, cc = c&7; scc = cc^(rl&7).
    const int rl0 = tid >> 3;
    const int scc0 = (tid & 7) ^ (rl0 & 7);
    const int8_t* srcA0 = qa + (size_t)(rowA0 + rl0) * K_TOT + scc0 * 16;
    const int dA0 = tid * 16, dA1 = (512 + tid) * 16;

    auto stageA = [&](int slot, int kt) {
        __builtin_amdgcn_global_load_lds(
            (const __attribute__((address_space(1))) void*)(srcA0 + kt * BK),
            (__attribute__((address_space(3))) void*)&ldsA[slot][dA0], 16, 0, 0);
        __builtin_amdgcn_global_load_lds(
            (const __attribute__((address_space(1))) void*)(srcA0 + (size_t)64 * K_TOT + kt * BK),
            (__attribute__((address_space(3))) void*)&ldsA[slot][dA1], 16, 0, 0);
    };

    auto ldA = [&](int slot, int mf, int ks) -> i32x4 {
        const int local = wr * 64 + mf * 16 + frow;
        const int ch = (ks * 4 + fq) ^ (local & 7);
        return *reinterpret_cast<const i32x4*>(&ldsA[slot][local * 128 + ch * 16]);
    };

    // B frag: col = rowB0 + wc*64 + nf*16 + frow; kt64 = T*2 + ks
    const int8_t* wbBase = wb2 + (size_t)(rowB0 + wc * 64 + frow) * 64 + fq * 16;
    i32x4 bF[4][2];
    auto loadB = [&](int T) {
        #pragma unroll
        for (int nf = 0; nf < 4; ++nf)
            #pragma unroll
            for (int ks = 0; ks < 2; ++ks)
                bF[nf][ks] = *reinterpret_cast<const i32x4*>(
                    wbBase + (size_t)(T * 2 + ks) * 65536 + nf * 1024);
    };

    // prologue: A(0)->s0, A(1)->s1, B(0)->regs   (order: A0, A1, B0)
    stageA(0, 0);
    stageA(1, 1);
    loadB(0);

    #pragma unroll 1
    for (int T = 0; T < NT; ++T) {
        const int sa = T % 3;
        if (T < NT - 1) asm volatile("s_waitcnt vmcnt(10)" ::: "memory");
        else            asm volatile("s_waitcnt vmcnt(0)" ::: "memory");
        __builtin_amdgcn_s_barrier();

        i32x4 aF[4];

        // ks = 0 half
        #pragma unroll
        for (int mf = 0; mf < 4; ++mf) aF[mf] = ldA(sa, mf, 0);
        if (T + 2 < NT) stageA((T + 2) % 3, T + 2);
        asm volatile("s_waitcnt lgkmcnt(0)" ::: "memory");
        __builtin_amdgcn_sched_barrier(0);
        __builtin_amdgcn_s_setprio(1);
        #pragma unroll
        for (int mf = 0; mf < 4; ++mf)
            #pragma unroll
            for (int nf = 0; nf < 4; ++nf)
                acc[mf][nf] = __builtin_amdgcn_mfma_i32_16x16x64_i8(
                    aF[mf], bF[nf][0], acc[mf][nf], 0, 0, 0);
        __builtin_amdgcn_s_setprio(0);

        // ks = 1 half
        #pragma unroll
        for (int mf = 0; mf < 4; ++mf) aF[mf] = ldA(sa, mf, 1);
        asm volatile("s_waitcnt lgkmcnt(0)" ::: "memory");
        __builtin_amdgcn_sched_barrier(0);
        __builtin_amdgcn_s_setprio(1);
        #pragma unroll
        for (int mf = 0; mf < 4; ++mf)
            #pragma unroll
            for (int nf = 0; nf < 4; ++nf)
                acc[mf][nf] = __builtin_amdgcn_mfma_i32_16x16x64_i8(
                    aF[mf], bF[nf][1], acc[mf][nf], 0, 0, 0);
        __builtin_amdgcn_s_setprio(0);

        if (T + 1 < NT) loadB(T + 1);   // overwrites bF after last use
    }

    // epilogue: C/D 16x16 layout: col = lane&15, row = fq*4 + reg. acc exact in i32.
    #pragma unroll
    for (int mf = 0; mf < 4; ++mf) {
        #pragma unroll
        for (int j = 0; j < 4; ++j) {
            const int gm = rowA0 + wr * 64 + mf * 16 + fq * 4 + j;
            const float sc = inv_row[gm];
            #pragma unroll
            for (int nf = 0; nf < 4; ++nf) {
                const int gn = rowB0 + wc * 64 + nf * 16 + frow;
                out[(size_t)gm * N_TOT + gn] = (float)acc[mf][nf][j] * sc + bias[gn];
            }
        }
    }
}

extern "C" void kernel_launch(void* const* d_in, const int* in_sizes, int n_in,
                              void* d_out, int out_size, void* d_ws, size_t ws_size,
                              hipStream_t stream) {
    const float* x = (const float*)d_in[0];
    const int* packed = (const int*)d_in[1];
    const float* wscale = (const float*)d_in[2];
    const float* bias = (const float*)d_in[3];
    float* out = (float*)d_out;

    int8_t* q = (int8_t*)d_ws;                                          // 32 MiB
    int8_t* wt2 = (int8_t*)((char*)d_ws + (size_t)M_TOT * K_TOT);       // 1 MiB
    float* inv_row = (float*)((char*)d_ws + (size_t)M_TOT * K_TOT + (size_t)N_TOT * K_TOT);

    quant_kernel<<<M_TOT, 256, 0, stream>>>(x, wscale, q, inv_row);
    unpack_kernel<<<OUT_F, 256, 0, stream>>>(packed, wt2);
    gemm_kernel<<<(M_TOT / BM) * (N_TOT / BN), 512, 0, stream>>>(q, wt2, inv_row, bias, out);
}